// Round 2
// baseline (18910.498 us; speedup 1.0000x reference)
//
#include <hip/hip_runtime.h>
#include <hip/hip_bf16.h>

#define Bn   1024
#define Tn   730
#define INn  64
#define Hn   512
#define Kn   576      // INn + Hn
#define G4n  2048     // 4*Hn

typedef __bf16 bf16x8 __attribute__((ext_vector_type(8)));
typedef float  f32x4  __attribute__((ext_vector_type(4)));

// ---------------- weight pre-pack: Wc[row][k] bf16, row = gate*512+j, k over [x|h] ----------
__global__ void convert_weights(const float* __restrict__ Wih,
                                const float* __restrict__ Whh,
                                __bf16* __restrict__ Wc) {
    int idx = blockIdx.x * 256 + threadIdx.x;
    if (idx >= G4n * Kn) return;
    int row = idx / Kn;
    int k   = idx - row * Kn;
    float v = (k < INn) ? Wih[row * INn + k] : Whh[row * Hn + (k - INn)];
    Wc[idx] = (__bf16)v;
}

__device__ __forceinline__ float sigf(float x)   { return 1.0f / (1.0f + __expf(-x)); }
__device__ __forceinline__ float tanhf_f(float x){ return 2.0f * sigf(2.0f * x) - 1.0f; }

// ---------------- one LSTM timestep ----------------
// grid: 512 blocks = 16 m-tiles (64 batch rows) x 32 j-tiles (16 cols)
// block: 256 threads = 4 waves; wave w owns rows m0+16w..+15, all 16 j-cols, all 4 gates.
__global__ void lstm_step(int t,
                          const float* __restrict__ xd,     // [B,T,IN]
                          const float* __restrict__ bias,   // [4H]
                          const __bf16* __restrict__ Wc,    // [4H][Kn]
                          const __bf16* __restrict__ hread, // [B,H]
                          __bf16* __restrict__ hwrite,      // [B,H]
                          float* __restrict__ c_state)      // [B,H]
{
    const int blk  = blockIdx.x;
    const int nj   = blk & 31;         // 32 j-tiles
    const int mi   = blk >> 5;         // 16 m-tiles
    const int m0   = mi << 6;          // 64 rows per m-tile
    const int j0   = nj << 4;          // 16 cols per j-tile
    const int tid  = threadIdx.x;
    const int wave = tid >> 6;
    const int lane = tid & 63;
    const int q    = lane >> 4;        // k-quad
    const int l16  = lane & 15;

    const int rowA = m0 + (wave << 4) + l16;     // batch row this lane loads for A

    // B-operand row pointers (one weight row per lane per gate), k-contiguous
    const __bf16* wp0 = Wc + (size_t)(0 * Hn + j0 + l16) * Kn + q * 8;
    const __bf16* wp1 = Wc + (size_t)(1 * Hn + j0 + l16) * Kn + q * 8;
    const __bf16* wp2 = Wc + (size_t)(2 * Hn + j0 + l16) * Kn + q * 8;
    const __bf16* wp3 = Wc + (size_t)(3 * Hn + j0 + l16) * Kn + q * 8;

    const int jj = j0 + l16;
    const float bi_ = bias[jj];
    const float bf_ = bias[Hn + jj];
    const float bg_ = bias[2 * Hn + jj];
    const float bo_ = bias[3 * Hn + jj];

    f32x4 ai = {0.f, 0.f, 0.f, 0.f};
    f32x4 af = {0.f, 0.f, 0.f, 0.f};
    f32x4 ag = {0.f, 0.f, 0.f, 0.f};
    f32x4 ao = {0.f, 0.f, 0.f, 0.f};

    // ---- K-iters 0..1: x features (fp32 -> bf16 on the fly) ----
    const float* xrow = xd + (size_t)rowA * (Tn * INn) + (size_t)t * INn + q * 8;
    #pragma unroll
    for (int kb = 0; kb < 2; ++kb) {
        const float* xp = xrow + kb * 32;
        f32x4 xlo = *(const f32x4*)xp;
        f32x4 xhi = *(const f32x4*)(xp + 4);
        bf16x8 a;
        a[0] = (__bf16)xlo[0]; a[1] = (__bf16)xlo[1];
        a[2] = (__bf16)xlo[2]; a[3] = (__bf16)xlo[3];
        a[4] = (__bf16)xhi[0]; a[5] = (__bf16)xhi[1];
        a[6] = (__bf16)xhi[2]; a[7] = (__bf16)xhi[3];
        const int ko = kb * 32;
        ai = __builtin_amdgcn_mfma_f32_16x16x32_bf16(a, *(const bf16x8*)(wp0 + ko), ai, 0, 0, 0);
        af = __builtin_amdgcn_mfma_f32_16x16x32_bf16(a, *(const bf16x8*)(wp1 + ko), af, 0, 0, 0);
        ag = __builtin_amdgcn_mfma_f32_16x16x32_bf16(a, *(const bf16x8*)(wp2 + ko), ag, 0, 0, 0);
        ao = __builtin_amdgcn_mfma_f32_16x16x32_bf16(a, *(const bf16x8*)(wp3 + ko), ao, 0, 0, 0);
    }

    // ---- K-iters 2..17: h features (bf16 direct) ----
    const __bf16* hrow = hread + (size_t)rowA * Hn + q * 8;
    #pragma unroll
    for (int kb = 2; kb < 18; ++kb) {
        bf16x8 a = *(const bf16x8*)(hrow + (kb - 2) * 32);
        const int ko = kb * 32;
        ai = __builtin_amdgcn_mfma_f32_16x16x32_bf16(a, *(const bf16x8*)(wp0 + ko), ai, 0, 0, 0);
        af = __builtin_amdgcn_mfma_f32_16x16x32_bf16(a, *(const bf16x8*)(wp1 + ko), af, 0, 0, 0);
        ag = __builtin_amdgcn_mfma_f32_16x16x32_bf16(a, *(const bf16x8*)(wp2 + ko), ag, 0, 0, 0);
        ao = __builtin_amdgcn_mfma_f32_16x16x32_bf16(a, *(const bf16x8*)(wp3 + ko), ao, 0, 0, 0);
    }

    // ---- gate pointwise, fully in-register (each (b,j) owned by exactly one lane/reg) ----
    const int browBase = m0 + (wave << 4) + (q << 2);  // C/D: row = quad*4 + reg
    #pragma unroll
    for (int r = 0; r < 4; ++r) {
        const int b = browBase + r;
        const size_t off = (size_t)b * Hn + jj;
        const float zi = ai[r] + bi_;
        const float zf = af[r] + bf_;
        const float zg = ag[r] + bg_;
        const float zo = ao[r] + bo_;
        const float cold = c_state[off];
        const float cn = sigf(zf) * cold + sigf(zi) * tanhf_f(zg);
        c_state[off] = cn;
        hwrite[off] = (__bf16)(sigf(zo) * tanhf_f(cn));
    }
}

// ---------------- head: out[b] = relu(dot(h_T[b], Wl) + bl) ----------------
__global__ void head_kernel(const __bf16* __restrict__ h, const float* __restrict__ Wl,
                            const float* __restrict__ bl, float* __restrict__ out) {
    const int b = blockIdx.x;
    const int lane = threadIdx.x;  // 64 threads
    const __bf16* hp = h + (size_t)b * Hn;
    float s = 0.f;
    #pragma unroll
    for (int j = lane; j < Hn; j += 64) s += (float)hp[j] * Wl[j];
    #pragma unroll
    for (int off = 32; off > 0; off >>= 1) s += __shfl_down(s, off, 64);
    if (lane == 0) out[b] = fmaxf(s + bl[0], 0.0f);
}

extern "C" void kernel_launch(void* const* d_in, const int* in_sizes, int n_in,
                              void* d_out, int out_size, void* d_ws, size_t ws_size,
                              hipStream_t stream) {
    const float* xd  = (const float*)d_in[0];
    const float* Wih = (const float*)d_in[1];
    const float* Whh = (const float*)d_in[2];
    const float* b   = (const float*)d_in[3];
    const float* Wl  = (const float*)d_in[4];
    const float* bl  = (const float*)d_in[5];
    float* out = (float*)d_out;

    // ws layout:
    //   Wc  bf16 [2048][576] : 2,359,296 B
    //   h0  bf16 [1024][512] : 1,048,576 B
    //   h1  bf16 [1024][512] : 1,048,576 B
    //   c   f32  [1024][512] : 2,097,152 B   (total ~6.4 MB)
    char* ws = (char*)d_ws;
    __bf16* Wc = (__bf16*)ws;
    __bf16* h0 = (__bf16*)(ws + 2359296);
    __bf16* h1 = (__bf16*)(ws + 2359296 + 1048576);
    float*  c  = (float*) (ws + 2359296 + 2 * 1048576);

    hipMemsetAsync(h0, 0, 1048576, stream);
    hipMemsetAsync(c,  0, 2097152, stream);

    const int total = G4n * Kn;
    convert_weights<<<(total + 255) / 256, 256, 0, stream>>>(Wih, Whh, Wc);

    for (int t = 0; t < Tn; ++t) {
        const __bf16* hr = (t & 1) ? h1 : h0;
        __bf16*       hw = (t & 1) ? h0 : h1;
        lstm_step<<<512, 256, 0, stream>>>(t, xd, b, Wc, hr, hw, c);
    }
    // t=729 (odd) writes h0 -> final hidden state is in h0
    head_kernel<<<Bn, 64, 0, stream>>>(h0, Wl, bl, out);
}